// Round 2
// baseline (434.109 us; speedup 1.0000x reference)
//
#include <hip/hip_runtime.h>
#include <math.h>

// Problem constants (fixed by setup_inputs)
#define OLDN   262144
#define NEWN   65536
#define BATCHN 4
#define NVAL   64
#define BVC    256          // NVAL * BATCHN columns of x_flat
#define R_TILE 32           // segments per block (32 -> 128B index-write bursts)
#define CAP    512          // LDS capacity for a tile's children (avg ~128)
#define UNR    16           // gather loads in flight per thread (branch-free)

// Pass 1: segment starts from sorted row[] — one coalesced sweep, no binsearch.
__global__ __launch_bounds__(256) void seg_starts_kernel(
    const int* __restrict__ row, int* __restrict__ starts, int nnz)
{
    int i = blockIdx.x * 256 + threadIdx.x;
    if (i < nnz) {
        if (i == 0) {
            starts[row[0]] = 0;
            starts[NEWN]   = nnz;
        } else if (row[i] != row[i - 1]) {
            starts[row[i]] = i;
        }
    }
}

__global__ __launch_bounds__(256, 4) void maxvalpool_kernel(
    const float* __restrict__ x,      // [B, OLDN, NVAL]
    const float* __restrict__ w,      // [nnz]
    const int*   __restrict__ row,    // [nnz] sorted (fallback path only)
    const int*   __restrict__ col,    // [nnz] permutation of OLDN
    const int*   __restrict__ starts, // [NEWN+1] from pass 1
    float*       __restrict__ out,    // pooled | nnz_ind[0] | nnz_ind[1]
    int nnz)
{
    __shared__ int   s_start[R_TILE + 1];
    // Packed per-child metadata: .x = (rr<<18) | col  (col < 2^18, rr < 32),
    // .y = weight bits. One ds_read_b64 per element (was 3x ds_read_b32) —
    // all lanes read the same address -> broadcast, conflict-free.
    __shared__ int2  s_meta[CAP + UNR];
    // winner col per (rr, thread). Stored at [rr][t ^ rr] so BOTH the flush
    // write (t varies, rr uniform -> XOR by uniform permutes banks: free) and
    // the transposed read (rr varies, t fixed -> tsrc^rr hits all 32 banks:
    // free) are conflict-free.
    __shared__ int   s_bestcol[R_TILE * BVC];

    const int t  = threadIdx.x;
    const int r0 = blockIdx.x * R_TILE;

    if (t <= R_TILE) s_start[t] = starts[r0 + t];
    __syncthreads();

    const int s0      = s_start[0];
    const int cnt     = s_start[R_TILE] - s0;
    const int cnt_pad = (cnt + UNR - 1) & ~(UNR - 1);
    const bool use_lds = (cnt <= CAP);
    if (use_lds) {
        for (int i = t; i < cnt_pad; i += 256) {
            if (i < cnt) {
                const int rr = row[s0 + i] - r0;
                s_meta[i] = make_int2((rr << 18) | col[s0 + i],
                                      __float_as_int(w[s0 + i]));
            } else {
                // Sentinel: NaN weight -> wv=NaN -> (wv > best) always false.
                // rr = R_TILE-1 == rr of last real element (last segment
                // non-empty), so no spurious segment flush.
                s_meta[i] = make_int2((R_TILE - 1) << 18, 0x7fc00000);
            }
        }
    }
    __syncthreads();

    const int b = t >> 6;        // batch index (wave id)
    const int v = t & 63;        // value index (lane) -> 256 B coalesced gathers
    const float* xb = x + (size_t)b * (OLDN * NVAL) + v;

    if (use_lds) {
        int   cur      = 0;           // starts[] is exact, segment r0 non-empty
        float best_wv  = -INFINITY;
        float best_val = 0.f;
        int   best_col = 0;
        for (int base = 0; base < cnt_pad; base += UNR) {
            // Branch-free: UNR independent gathers in flight before any use.
            int2 ms[UNR];
            #pragma unroll
            for (int u = 0; u < UNR; ++u) ms[u] = s_meta[base + u];
            float vals[UNR];
            #pragma unroll
            for (int u = 0; u < UNR; ++u)
                vals[u] = __builtin_nontemporal_load(
                    &xb[(size_t)(ms[u].x & 0x3FFFF) * NVAL]);
            #pragma unroll
            for (int u = 0; u < UNR; ++u) {
                const int rr = ms[u].x >> 18;
                if (rr != cur) {   // uniform branch: segment boundary -> flush winner
                    __builtin_nontemporal_store(
                        best_val, &out[((size_t)b * NEWN + (r0 + cur)) * NVAL + v]);
                    s_bestcol[cur * BVC + (t ^ cur)] = best_col;
                    best_wv = -INFINITY;
                    cur = rr;
                }
                const float wv = __int_as_float(ms[u].y) * vals[u];  // exact fp32 mul
                if (wv > best_wv) {                        // strict > == min-index tie-break
                    best_wv = wv; best_val = vals[u]; best_col = ms[u].x & 0x3FFFF;
                }
            }
        }
        __builtin_nontemporal_store(
            best_val, &out[((size_t)b * NEWN + (r0 + cur)) * NVAL + v]);
        s_bestcol[cur * BVC + (t ^ cur)] = best_col;
    } else {
        // Defensive fallback (tile children > CAP) — unreachable for this dataset
        for (int rr = 0; rr < R_TILE; ++rr) {
            const int e0 = s_start[rr], e1 = s_start[rr + 1];
            float best_wv = -INFINITY, best_val = 0.f;
            int best_col = 0;
            for (int i = e0; i < e1; ++i) {
                const int   cc  = col[i];
                const float val = xb[(size_t)cc * NVAL];
                const float wv  = w[i] * val;
                if (wv > best_wv) { best_wv = wv; best_val = val; best_col = cc; }
            }
            out[((size_t)b * NEWN + (r0 + rr)) * NVAL + v] = best_val;
            s_bestcol[rr * BVC + (t ^ rr)] = best_col;
        }
    }
    __syncthreads();

    // Transposed index writes: out2[k, cc*NEWN + r]; per wave: 2 cc-groups of
    // 32 consecutive r -> two 128 B bursts. Nontemporal: never re-read.
    float* out2  = out  + (size_t)BATCHN * NEWN * NVAL;  // nnz_ind[0]
    float* out2b = out2 + (size_t)BVC * NEWN;            // nnz_ind[1]
    #pragma unroll
    for (int j = 0; j < (BVC * R_TILE) / 256; ++j) {
        const int e  = j * 256 + t;
        const int cc = e >> 5;            // x_flat column
        const int rr = e & (R_TILE - 1);  // segment within tile
        // thread that owned column cc: c = (v<<2)|b  =>  t = ((cc&3)<<6)|(cc>>2)
        const int tsrc = ((cc & 3) << 6) | (cc >> 2);
        const int bc = s_bestcol[rr * BVC + (tsrc ^ rr)];
        const size_t o = (size_t)cc * NEWN + (r0 + rr);
        __builtin_nontemporal_store((float)bc, &out2[o]);   // winning old-node index
        __builtin_nontemporal_store((float)cc, &out2b[o]);  // column index
    }
}

extern "C" void kernel_launch(void* const* d_in, const int* in_sizes, int n_in,
                              void* d_out, int out_size, void* d_ws, size_t ws_size,
                              hipStream_t stream) {
    const float* x   = (const float*)d_in[0];
    const float* w   = (const float*)d_in[1];
    const int*   row = (const int*)d_in[2];
    const int*   col = (const int*)d_in[3];
    float*       out = (float*)d_out;
    int*         starts = (int*)d_ws;     // NEWN+1 ints
    const int nnz = in_sizes[3];          // 262144

    seg_starts_kernel<<<(nnz + 255) / 256, 256, 0, stream>>>(row, starts, nnz);

    dim3 grid(NEWN / R_TILE);
    dim3 block(256);
    maxvalpool_kernel<<<grid, block, 0, stream>>>(x, w, row, col, starts, out, nnz);
}